// Round 11
// baseline (326.593 us; speedup 1.0000x reference)
//
#include <hip/hip_runtime.h>
#include <hip/hip_bf16.h>

typedef __attribute__((ext_vector_type(4))) float f4;
typedef __attribute__((ext_vector_type(4))) float f32x4;
typedef __attribute__((ext_vector_type(8))) short short8;
typedef __attribute__((ext_vector_type(2))) unsigned int u32x2;
typedef __attribute__((ext_vector_type(4))) unsigned int u32x4;
typedef unsigned int u32;
typedef unsigned short u16;

#define SCALE_F 0.04419417382415922f   // 1/sqrt(512)

__device__ inline u16 f2bf(float f) {
  u32 u = __float_as_uint(f);
  u32 r = u + 0x7FFFu + ((u >> 16) & 1u);
  return (u16)(r >> 16);
}
__device__ inline u32 pk(float a, float b) {
  return (u32)f2bf(a) | ((u32)f2bf(b) << 16);
}
__device__ inline float bflo(u32 u) { return __uint_as_float(u << 16); }
__device__ inline float bfhi(u32 u) { return __uint_as_float(u & 0xFFFF0000u); }

// async global->LDS, 16B per lane; LDS dest must be wave-uniform base + lane*16
#define GLD16(gsrc, ldst)                                                     \
  __builtin_amdgcn_global_load_lds(                                           \
      (const __attribute__((address_space(1))) void*)(gsrc),                  \
      (__attribute__((address_space(3))) void*)(ldst), 16, 0, 0)

// byte-offset swizzle: 16B slot s within a 2048B row gets XOR'd by (row&7).
// xpre is stored LINEAR; the swizzle is applied on the READ address only.
#define SWZ(o) (((o) & ~2047) | (((((o) >> 4) & 127) ^ (((o) >> 11) & 7)) << 4))

// ---------------- K01: merged x-prep + weight prep ----------------
// Read-once streams use NONTEMPORAL loads so they don't evict xpre from L3.
__device__ __forceinline__ void cvt8(const float* __restrict__ src,
                                     u16* __restrict__ dst, int blk, int t) {
  int i = blk * 256 + t;
  const f4* s = (const f4*)src;
  f4 a = __builtin_nontemporal_load(s + (size_t)i * 2);
  f4 b = __builtin_nontemporal_load(s + (size_t)i * 2 + 1);
  u32x4 p;
  p[0] = pk(a[0], a[1]);
  p[1] = pk(a[2], a[3]);
  p[2] = pk(b[0], b[1]);
  p[3] = pk(b[2], b[3]);
  *(u32x4*)(dst + (size_t)i * 8) = p;
}

__global__ __launch_bounds__(256) void k01_prep(const float* __restrict__ x,
                                                const float* __restrict__ Wg,
                                                const float* __restrict__ Wp,
                                                const float* __restrict__ Wt,
                                                u16* __restrict__ xs16,
                                                char* __restrict__ xpre,
                                                u16* __restrict__ wgb,
                                                u16* __restrict__ wpb,
                                                u16* __restrict__ wtb) {
  __shared__ float red[256][8];
  __shared__ u16 tile[64][66];
  const int blk = blockIdx.x, t = threadIdx.x;
  if (blk < 2048) {
    // ---- x prep: colsum + LINEAR bf16 echo (16B/lane coalesced writes) ----
    const int b = blk;
    const float* xb = x + (size_t)b * 65536;
    char* xp = xpre + (size_t)b * 131072;
    const int g16 = t & 127, rp = t >> 7;    // granule, row-parity
    f4 acc0 = {0.f, 0.f, 0.f, 0.f}, acc1 = {0.f, 0.f, 0.f, 0.f};
#pragma unroll 8
    for (int it = 0; it < 32; ++it) {
      int n = it * 2 + rp;
      const f4* src = (const f4*)(xb + n * 1024 + g16 * 8);
      f4 v0 = __builtin_nontemporal_load(src);
      f4 v1 = __builtin_nontemporal_load(src + 1);
      acc0 += v0;
      acc1 += v1;
      u32x4 p;
      p[0] = pk(v0[0], v0[1]);
      p[1] = pk(v0[2], v0[3]);
      p[2] = pk(v1[0], v1[1]);
      p[3] = pk(v1[2], v1[3]);
      *(u32x4*)(xp + n * 2048 + g16 * 16) = p;
    }
    *(f4*)&red[t][0] = acc0;
    *(f4*)&red[t][4] = acc1;
    __syncthreads();
    if (t < 128) {
      f4 s0 = *(const f4*)&red[t][0];
      f4 s1 = *(const f4*)&red[t][4];
      f4 q0 = *(const f4*)&red[t + 128][0];
      f4 q1 = *(const f4*)&red[t + 128][4];
      s0 += q0;
      s1 += q1;
      u32x4 p;
      p[0] = pk(s0[0], s0[1]);
      p[1] = pk(s0[2], s0[3]);
      p[2] = pk(s1[0], s1[1]);
      p[3] = pk(s1[2], s1[3]);
      *(u32x4*)(xs16 + (size_t)b * 1024 + t * 8) = p;
    }
  } else if (blk < 4096) {
    cvt8(Wg, wgb, blk - 2048, t);
  } else if (blk < 4608) {
    cvt8(Wp, wpb, blk - 4096, t);
  } else {
    const int bid = blk - 4608;
    const int g = bid >> 6, rem = bid & 63;
    const int f0 = (rem & 15) * 64, r0 = (rem >> 4) * 64;
    const float* src = Wt + ((size_t)g * 256 + r0) * 1024 + f0;
#pragma unroll
    for (int i = 0; i < 16; ++i) {
      int idx = t + i * 256;
      int rl = idx >> 6, fl = idx & 63;
      tile[fl][rl] = f2bf(__builtin_nontemporal_load(src + rl * 1024 + fl));
    }
    __syncthreads();
    u16* dst = wtb + ((size_t)g * 1024 + f0) * 256 + r0;
#pragma unroll
    for (int i = 0; i < 4; ++i) {
      int idx = t + i * 256;
      int fl = idx >> 4, rq = idx & 15;
      u32x2 p;
      p[0] = (u32)tile[fl][rq * 4]     | ((u32)tile[fl][rq * 4 + 1] << 16);
      p[1] = (u32)tile[fl][rq * 4 + 2] | ((u32)tile[fl][rq * 4 + 3] << 16);
      *(u32x2*)(dst + fl * 256 + rq * 4) = p;
    }
  }
}

// ---- K2: ps16[b,q] = bf16( xs16·Wp16 + 64*bp ), 128x64 tiles, grid (16,16) --
__global__ __launch_bounds__(256) void k2_gemm(const u16* __restrict__ A,
                                               const u16* __restrict__ Bt,
                                               const float* __restrict__ bp,
                                               u16* __restrict__ C) {
  const int n0 = blockIdx.x * 64, m0 = blockIdx.y * 128;
  __shared__ u16 Al[128 * 32];
  __shared__ u16 Bl[64 * 32];
  const int t = threadIdx.x;
  const int w = t >> 6, l = t & 63;
  const int lr = l & 15, lh = l >> 4;
  f32x4 acc[2][4] = {};
  for (int kt = 0; kt < 1024; kt += 32) {
#pragma unroll
    for (int j = 0; j < 2; ++j) {
      int idx = t + j * 256;
      int row = idx >> 2, sl = idx & 3;
      GLD16(A + (size_t)(m0 + row) * 1024 + kt + sl * 8, Al + idx * 8);
    }
    {
      int row = t >> 2, sl = t & 3;
      GLD16(Bt + (size_t)(n0 + row) * 1024 + kt + sl * 8, Bl + t * 8);
    }
    __syncthreads();
    short8 af[2], bfr[4];
#pragma unroll
    for (int m = 0; m < 2; ++m)
      af[m] = *(const short8*)(Al + (w * 32 + m * 16 + lr) * 32 + lh * 8);
#pragma unroll
    for (int n = 0; n < 4; ++n)
      bfr[n] = *(const short8*)(Bl + (n * 16 + lr) * 32 + lh * 8);
#pragma unroll
    for (int m = 0; m < 2; ++m)
#pragma unroll
      for (int n = 0; n < 4; ++n)
        acc[m][n] = __builtin_amdgcn_mfma_f32_16x16x32_bf16(af[m], bfr[n],
                                                            acc[m][n], 0, 0, 0);
    __syncthreads();
  }
#pragma unroll
  for (int m = 0; m < 2; ++m)
#pragma unroll
    for (int n = 0; n < 4; ++n) {
      int col = n0 + n * 16 + lr;
      float bb = 64.0f * bp[col];
#pragma unroll
      for (int j = 0; j < 4; ++j)
        C[(size_t)(m0 + w * 32 + m * 16 + lh * 4 + j) * 1024 + col] =
            f2bf(acc[m][n][j] + bb);
    }
}

// ------- K3: V16[g,b,f] = bf16( ps16·Wtt ), 1D grid 512 + XCD swizzle -------
__global__ __launch_bounds__(256) void k3_gemm(const u16* __restrict__ A,
                                               const u16* __restrict__ Btt,
                                               u16* __restrict__ Vb) {
  const int id = blockIdx.x;
  const int wg = (id & 7) * 64 + (id >> 3);   // bijective XCD chunking (512=64x8)
  const int n0 = (wg & 7) * 128, m0 = ((wg >> 3) & 15) * 128, g = wg >> 7;
  const u16* Bg = Btt + (size_t)g * 1024 * 256;
  __shared__ u16 Al[128 * 32];
  __shared__ u16 Bl[128 * 32];
  const int t = threadIdx.x;
  const int w = t >> 6, l = t & 63;
  const int wr = w >> 1, wc = w & 1;
  const int lr = l & 15, lh = l >> 4;
  f32x4 acc[4][4] = {};
  for (int kt = 0; kt < 256; kt += 32) {
#pragma unroll
    for (int j = 0; j < 2; ++j) {
      int idx = t + j * 256;
      int row = idx >> 2, sl = idx & 3;
      GLD16(A + (size_t)(m0 + row) * 1024 + g * 256 + kt + sl * 8, Al + idx * 8);
      GLD16(Bg + (size_t)(n0 + row) * 256 + kt + sl * 8, Bl + idx * 8);
    }
    __syncthreads();
    short8 af[4], bfr[4];
#pragma unroll
    for (int m = 0; m < 4; ++m)
      af[m] = *(const short8*)(Al + (wr * 64 + m * 16 + lr) * 32 + lh * 8);
#pragma unroll
    for (int n = 0; n < 4; ++n)
      bfr[n] = *(const short8*)(Bl + (wc * 64 + n * 16 + lr) * 32 + lh * 8);
#pragma unroll
    for (int m = 0; m < 4; ++m)
#pragma unroll
      for (int n = 0; n < 4; ++n)
        acc[m][n] = __builtin_amdgcn_mfma_f32_16x16x32_bf16(af[m], bfr[n],
                                                            acc[m][n], 0, 0, 0);
    __syncthreads();
  }
  u16* Vg = Vb + (size_t)g * 2048 * 1024;
#pragma unroll
  for (int m = 0; m < 4; ++m)
#pragma unroll
    for (int n = 0; n < 4; ++n)
#pragma unroll
      for (int j = 0; j < 4; ++j)
        Vg[(size_t)(m0 + wr * 64 + m * 16 + lh * 4 + j) * 1024 +
           (n0 + wc * 64 + n * 16 + lr)] = f2bf(acc[m][n][j]);
}

// ---------------- K4 phase helpers ----------------
__device__ __forceinline__ void relation_phase(const char* xl, const u16* vb,
                                               float* relp, int w, int l) {
  const int lg = l >> 4, lr = l & 15;
  f32x4 racc[4] = {};
#pragma unroll
  for (int kp = 0; kp < 2; ++kp) {
    const int kt = kp * 512 + w * 32;
    short8 afr = {};
    if (lr < 4) afr = *(const short8*)(vb + lr * 1032 + kt + lg * 8);
#pragma unroll
    for (int nt = 0; nt < 4; ++nt) {
      int n = nt * 16 + lr;
      short8 bfrg = *(const short8*)(
          xl + n * 2048 + ((((kt >> 3) + lg) ^ (n & 7)) << 4));
      racc[nt] = __builtin_amdgcn_mfma_f32_16x16x32_bf16(afr, bfrg, racc[nt],
                                                         0, 0, 0);
    }
  }
  // D (16x16x32): col = lane&15, row = (lane>>4)*4 + reg; lanes<16 rows 0..3=g
  if (l < 16) {
#pragma unroll
    for (int nt = 0; nt < 4; ++nt)
#pragma unroll
      for (int j = 0; j < 4; ++j)
        relp[(w * 4 + j) * 64 + nt * 16 + lr] = racc[nt][j];
  }
}

__device__ __forceinline__ void softmax_phase(const float* relp, float* wsm,
                                              int t) {
  if (t < 256) {
    const int g = t >> 6, n = t & 63;
    float rel = 0.f;
#pragma unroll
    for (int ww = 0; ww < 16; ++ww) rel += relp[(ww * 4 + g) * 64 + n];
    rel *= SCALE_F;
    float mx = rel;
#pragma unroll
    for (int o = 32; o > 0; o >>= 1) mx = fmaxf(mx, __shfl_xor(mx, o, 64));
    float e = __expf(rel - mx);
    float s = e;
#pragma unroll
    for (int o = 32; o > 0; o >>= 1) s += __shfl_xor(s, o, 64);
    wsm[t] = e / s;
  }
}

__device__ __forceinline__ void agg_phase(const char* xl, const float* wsm,
                                          float* relp, u16* aggb, int b,
                                          int t) {
  const int hh = t >> 9, r = t & 511, g = r >> 7, f8 = r & 127;
  const float* wg = wsm + g * 64 + hh * 32;
  float a0 = 0, a1 = 0, a2 = 0, a3 = 0, a4 = 0, a5 = 0, a6 = 0, a7 = 0;
#pragma unroll 8
  for (int n0 = 0; n0 < 32; ++n0) {
    int n = hh * 32 + n0;
    float wv = wg[n0];
    u32x4 xp = *(const u32x4*)(xl + n * 2048 + ((f8 ^ (n & 7)) << 4));
    a0 = fmaf(bflo(xp[0]), wv, a0);
    a1 = fmaf(bfhi(xp[0]), wv, a1);
    a2 = fmaf(bflo(xp[1]), wv, a2);
    a3 = fmaf(bfhi(xp[1]), wv, a3);
    a4 = fmaf(bflo(xp[2]), wv, a4);
    a5 = fmaf(bfhi(xp[2]), wv, a5);
    a6 = fmaf(bflo(xp[3]), wv, a6);
    a7 = fmaf(bfhi(xp[3]), wv, a7);
  }
  if (hh) {
    f4 q0 = {a0, a1, a2, a3};
    f4 q1 = {a4, a5, a6, a7};
    *(f4*)(relp + r * 8) = q0;
    *(f4*)(relp + r * 8 + 4) = q1;
  }
  __syncthreads();
  if (!hh) {
    f4 q0 = *(const f4*)(relp + r * 8);
    f4 q1 = *(const f4*)(relp + r * 8 + 4);
    u32x4 p;
    p[0] = pk(a0 + q0[0], a1 + q0[1]);
    p[1] = pk(a2 + q0[2], a3 + q0[3]);
    p[2] = pk(a4 + q1[0], a5 + q1[1]);
    p[3] = pk(a6 + q1[2], a7 + q1[3]);
    *(u32x4*)(aggb + ((size_t)g * 2048 + b) * 1024 + f8 * 8) = p;
  }
}

// ------ K4: grid 256 (1 block/CU), 8 b's per block, steady-state pipeline ---
// LDS: xl 128K swizzled bf16 | vb 8256B | relp 16K | wsm 1K
#define K4_LDS (131072 + 8256 + 16384 + 1024)
__global__ __launch_bounds__(1024) void k4_fused(const char* __restrict__ xpre,
                                                 const u16* __restrict__ vb16,
                                                 u16* __restrict__ aggb) {
  extern __shared__ char sm[];
  char* xl = sm;
  u16* vb = (u16*)(sm + 131072);
  float* relp = (float*)(sm + 131072 + 8256);
  float* wsm = (float*)(sm + 131072 + 8256 + 16384);
  const int t = threadIdx.x;
  const int w = t >> 6, l = t & 63;
  // reverse chunk order: xpre tail was written last by K01 -> L3-hot first
  const int bbase = (255 - (int)blockIdx.x) * 8;

  // ---- cold stage: b0 x via DMA (swizzled per-lane SOURCE, linear dest) ----
  {
    int g = t >> 8, q = t & 255;
    u32x2 pv = *(const u32x2*)(vb16 + ((size_t)g * 2048 + bbase) * 1024 + q * 4);
    *(u32x2*)(vb + g * 1032 + q * 4) = pv;
  }
  const char* xg0 = xpre + (size_t)bbase * 131072;
#pragma unroll
  for (int i = 0; i < 8; ++i) {
    int o = (w * 8 + i) * 1024 + l * 16;
    GLD16(xg0 + SWZ(o), xl + o);
  }
  __syncthreads();

  u32x4 pf0, pf1, pf2, pf3, pf4, pf5, pf6, pf7;
  u32x2 pv1;
  for (int ib = 0; ib < 8; ++ib) {
    const int b = bbase + ib;
    // issue next-b prefetch; lands during this b's compute
    if (ib < 7) {
      const char* xg1 = xpre + (size_t)(b + 1) * 131072;
      pf0 = *(const u32x4*)(xg1 + SWZ(t * 16));
      pf1 = *(const u32x4*)(xg1 + SWZ(t * 16 + 16384));
      pf2 = *(const u32x4*)(xg1 + SWZ(t * 16 + 32768));
      pf3 = *(const u32x4*)(xg1 + SWZ(t * 16 + 49152));
      pf4 = *(const u32x4*)(xg1 + SWZ(t * 16 + 65536));
      pf5 = *(const u32x4*)(xg1 + SWZ(t * 16 + 81920));
      pf6 = *(const u32x4*)(xg1 + SWZ(t * 16 + 98304));
      pf7 = *(const u32x4*)(xg1 + SWZ(t * 16 + 114688));
      pv1 = *(const u32x2*)(vb16 + ((size_t)(t >> 8) * 2048 + (b + 1)) * 1024 +
                            (t & 255) * 4);
    }
    // ---- compute current b ----
    relation_phase(xl, vb, relp, w, l);
    __syncthreads();
    softmax_phase(relp, wsm, t);
    __syncthreads();
    agg_phase(xl, wsm, relp, aggb, b, t);
    __syncthreads();                     // all xl reads for this b done
    // ---- stage next b from regs ----
    if (ib < 7) {
      *(u32x4*)(xl + t * 16) = pf0;
      *(u32x4*)(xl + t * 16 + 16384) = pf1;
      *(u32x4*)(xl + t * 16 + 32768) = pf2;
      *(u32x4*)(xl + t * 16 + 49152) = pf3;
      *(u32x4*)(xl + t * 16 + 65536) = pf4;
      *(u32x4*)(xl + t * 16 + 81920) = pf5;
      *(u32x4*)(xl + t * 16 + 98304) = pf6;
      *(u32x4*)(xl + t * 16 + 114688) = pf7;
      *(u32x2*)(vb + (t >> 8) * 1032 + (t & 255) * 4) = pv1;
      __syncthreads();
    }
  }
}

// -- K5: h16 = bf16( agg·Wg^T ) (MFMA), 1D grid 512 + bijective XCD swizzle --
__global__ __launch_bounds__(256) void k5_gemm(const u16* __restrict__ Ab,
                                               const u16* __restrict__ Bb,
                                               u16* __restrict__ H) {
  const int id = blockIdx.x;
  const int wg = (id & 7) * 64 + (id >> 3);   // per-XCD: g fixed, 4MB footprint
  const int n0 = (wg & 7) * 128, m0 = ((wg >> 3) & 15) * 128, g = wg >> 7;
  const u16* A = Ab + (size_t)g * 2048 * 1024;
  const u16* Bt = Bb + (size_t)g * 1024 * 1024;
  __shared__ u16 Al[128 * 32];
  __shared__ u16 Bl[128 * 32];
  const int t = threadIdx.x;
  const int w = t >> 6, l = t & 63;
  const int wr = w >> 1, wc = w & 1;
  const int lr = l & 15, lh = l >> 4;
  f32x4 acc[4][4] = {};
  for (int kt = 0; kt < 1024; kt += 32) {
#pragma unroll
    for (int j = 0; j < 2; ++j) {
      int idx = t + j * 256;
      int row = idx >> 2, sl = idx & 3;
      GLD16(A + (size_t)(m0 + row) * 1024 + kt + sl * 8, Al + idx * 8);
      GLD16(Bt + (size_t)(n0 + row) * 1024 + kt + sl * 8, Bl + idx * 8);
    }
    __syncthreads();
    short8 af[4], bfr[4];
#pragma unroll
    for (int m = 0; m < 4; ++m)
      af[m] = *(const short8*)(Al + (wr * 64 + m * 16 + lr) * 32 + lh * 8);
#pragma unroll
    for (int n = 0; n < 4; ++n)
      bfr[n] = *(const short8*)(Bl + (wc * 64 + n * 16 + lr) * 32 + lh * 8);
#pragma unroll
    for (int m = 0; m < 4; ++m)
#pragma unroll
      for (int n = 0; n < 4; ++n)
        acc[m][n] = __builtin_amdgcn_mfma_f32_16x16x32_bf16(af[m], bfr[n],
                                                            acc[m][n], 0, 0, 0);
    __syncthreads();
  }
  u16* Hg = H + (size_t)g * 2048 * 1024;
#pragma unroll
  for (int m = 0; m < 4; ++m)
#pragma unroll
    for (int n = 0; n < 4; ++n)
#pragma unroll
      for (int j = 0; j < 4; ++j)
        Hg[(size_t)(m0 + wr * 64 + m * 16 + lh * 4 + j) * 1024 +
           (n0 + wc * 64 + n * 16 + lr)] = f2bf(acc[m][n][j]);
}

// ---------------- K6: LayerNorm + ReLU + mean over g (bf16 H) ----------------
__global__ __launch_bounds__(256) void k6_ln(const u16* __restrict__ H,
                                             const float* __restrict__ gamma,
                                             const float* __restrict__ beta,
                                             float* __restrict__ out) {
  const int b = blockIdx.x, t = threadIdx.x;
  const int w = t >> 6, lane = t & 63;
  __shared__ float red[8];
  f4 acc = {0.f, 0.f, 0.f, 0.f};
  for (int g = 0; g < 4; ++g) {
    u32x2 hp = __builtin_nontemporal_load(
        (const u32x2*)(H + ((size_t)g * 2048 + b) * 1024 + t * 4));
    f4 hv = {bflo(hp[0]), bfhi(hp[0]), bflo(hp[1]), bfhi(hp[1])};
    float s = hv[0] + hv[1] + hv[2] + hv[3];
    float q = hv[0] * hv[0] + hv[1] * hv[1] + hv[2] * hv[2] + hv[3] * hv[3];
#pragma unroll
    for (int o = 32; o > 0; o >>= 1) {
      s += __shfl_xor(s, o, 64);
      q += __shfl_xor(q, o, 64);
    }
    if (lane == 0) { red[w] = s; red[4 + w] = q; }
    __syncthreads();
    s = red[0] + red[1] + red[2] + red[3];
    q = red[4] + red[5] + red[6] + red[7];
    float mean = s * (1.f / 1024.f);
    float var = q * (1.f / 1024.f) - mean * mean;
    float rstd = rsqrtf(var + 1e-5f);
    f4 gm = *(const f4*)(gamma + g * 1024 + t * 4);
    f4 bt = *(const f4*)(beta + g * 1024 + t * 4);
#pragma unroll
    for (int j = 0; j < 4; ++j) {
      float val = (hv[j] - mean) * rstd * gm[j] + bt[j];
      acc[j] += fmaxf(val, 0.f);
    }
    __syncthreads();
  }
  acc *= 0.25f;
  __builtin_nontemporal_store(acc, (f4*)(out + (size_t)b * 1024 + t * 4));
}

extern "C" void kernel_launch(void* const* d_in, const int* in_sizes, int n_in,
                              void* d_out, int out_size, void* d_ws, size_t ws_size,
                              hipStream_t stream) {
  const float* x     = (const float*)d_in[0];
  const float* Wt    = (const float*)d_in[1];
  // d_in[2] = bt: n-constant in relation -> cancels in softmax, unused
  const float* Wp    = (const float*)d_in[3];
  const float* bp    = (const float*)d_in[4];
  const float* Wg    = (const float*)d_in[5];
  const float* gamma = (const float*)d_in[6];
  const float* beta  = (const float*)d_in[7];
  float* out = (float*)d_out;

  char* ws = (char*)d_ws;
  u16*   xs16 = (u16*)(ws);                          //  4 MiB
  u16*   ps16 = (u16*)(ws + (4u << 20));             //  4 MiB
  u16*   wpb  = (u16*)(ws + (8u << 20));             //  2 MiB
  u16*   wtb  = (u16*)(ws + (10u << 20));            //  2 MiB
  u16*   wgb  = (u16*)(ws + (12u << 20));            //  8 MiB
  u16*   vb16 = (u16*)(ws + (20u << 20));            // 16 MiB
  u16*   aggb = (u16*)(ws + (36u << 20));            // 16 MiB
  u16*   hb16 = (u16*)(ws + (52u << 20));            // 16 MiB
  char*  xpre = (char*)(ws + (68u << 20));           // 256 MiB (LINEAR bf16)

  hipFuncSetAttribute((const void*)k4_fused,
                      hipFuncAttributeMaxDynamicSharedMemorySize, K4_LDS);

  k01_prep<<<4864, 256, 0, stream>>>(x, Wg, Wp, Wt, xs16, xpre, wgb, wpb, wtb);
  k2_gemm<<<dim3(16, 16), 256, 0, stream>>>(xs16, wpb, bp, ps16);
  k3_gemm<<<512, 256, 0, stream>>>(ps16, wtb, vb16);
  k4_fused<<<256, 1024, K4_LDS, stream>>>(xpre, vb16, aggb);
  k5_gemm<<<512, 256, 0, stream>>>(aggb, wgb, hb16);
  k6_ln<<<2048, 256, 0, stream>>>(hb16, gamma, beta, out);
}

// Round 12
// 308.069 us; speedup vs baseline: 1.0601x; 1.0601x over previous
//
#include <hip/hip_runtime.h>
#include <hip/hip_bf16.h>

typedef __attribute__((ext_vector_type(4))) float f4;
typedef __attribute__((ext_vector_type(4))) float f32x4;
typedef __attribute__((ext_vector_type(8))) short short8;
typedef __attribute__((ext_vector_type(2))) unsigned int u32x2;
typedef __attribute__((ext_vector_type(4))) unsigned int u32x4;
typedef unsigned int u32;
typedef unsigned short u16;

#define SCALE_F 0.04419417382415922f   // 1/sqrt(512)

__device__ inline u16 f2bf(float f) {
  u32 u = __float_as_uint(f);
  u32 r = u + 0x7FFFu + ((u >> 16) & 1u);
  return (u16)(r >> 16);
}
__device__ inline u32 pk(float a, float b) {
  return (u32)f2bf(a) | ((u32)f2bf(b) << 16);
}
__device__ inline float bflo(u32 u) { return __uint_as_float(u << 16); }
__device__ inline float bfhi(u32 u) { return __uint_as_float(u & 0xFFFF0000u); }

// async global->LDS, 16B per lane; LDS dest must be wave-uniform base + lane*16
#define GLD16(gsrc, ldst)                                                     \
  __builtin_amdgcn_global_load_lds(                                           \
      (const __attribute__((address_space(1))) void*)(gsrc),                  \
      (__attribute__((address_space(3))) void*)(ldst), 16, 0, 0)

// byte-offset swizzle: 16B slot s within a 2048B row gets XOR'd by (row&7).
// xpre is stored LINEAR; the swizzle is applied on the READ address only.
#define SWZ(o) (((o) & ~2047) | (((((o) >> 4) & 127) ^ (((o) >> 11) & 7)) << 4))

// ---------------- K01: merged x-prep + weight prep ----------------
__device__ __forceinline__ void cvt8(const float* __restrict__ src,
                                     u16* __restrict__ dst, int blk, int t) {
  int i = blk * 256 + t;
  const f4* s = (const f4*)src;
  f4 a = s[(size_t)i * 2];
  f4 b = s[(size_t)i * 2 + 1];
  u32x4 p;
  p[0] = pk(a[0], a[1]);
  p[1] = pk(a[2], a[3]);
  p[2] = pk(b[0], b[1]);
  p[3] = pk(b[2], b[3]);
  *(u32x4*)(dst + (size_t)i * 8) = p;
}

__global__ __launch_bounds__(256) void k01_prep(const float* __restrict__ x,
                                                const float* __restrict__ Wg,
                                                const float* __restrict__ Wp,
                                                const float* __restrict__ Wt,
                                                u16* __restrict__ xs16,
                                                char* __restrict__ xpre,
                                                u16* __restrict__ wgb,
                                                u16* __restrict__ wpb,
                                                u16* __restrict__ wtb) {
  __shared__ float red[256][8];
  __shared__ u16 tile[64][66];
  const int blk = blockIdx.x, t = threadIdx.x;
  if (blk < 2048) {
    // ---- x prep: colsum + LINEAR bf16 echo (16B/lane coalesced writes) ----
    const int b = blk;
    const float* xb = x + (size_t)b * 65536;
    char* xp = xpre + (size_t)b * 131072;
    const int g16 = t & 127, rp = t >> 7;    // granule, row-parity
    f4 acc0 = {0.f, 0.f, 0.f, 0.f}, acc1 = {0.f, 0.f, 0.f, 0.f};
#pragma unroll 8
    for (int it = 0; it < 32; ++it) {
      int n = it * 2 + rp;
      const float* src = xb + n * 1024 + g16 * 8;
      f4 v0 = *(const f4*)(src);
      f4 v1 = *(const f4*)(src + 4);
      acc0 += v0;
      acc1 += v1;
      u32x4 p;
      p[0] = pk(v0[0], v0[1]);
      p[1] = pk(v0[2], v0[3]);
      p[2] = pk(v1[0], v1[1]);
      p[3] = pk(v1[2], v1[3]);
      *(u32x4*)(xp + n * 2048 + g16 * 16) = p;
    }
    *(f4*)&red[t][0] = acc0;
    *(f4*)&red[t][4] = acc1;
    __syncthreads();
    if (t < 128) {
      f4 s0 = *(const f4*)&red[t][0];
      f4 s1 = *(const f4*)&red[t][4];
      f4 q0 = *(const f4*)&red[t + 128][0];
      f4 q1 = *(const f4*)&red[t + 128][4];
      s0 += q0;
      s1 += q1;
      u32x4 p;
      p[0] = pk(s0[0], s0[1]);
      p[1] = pk(s0[2], s0[3]);
      p[2] = pk(s1[0], s1[1]);
      p[3] = pk(s1[2], s1[3]);
      *(u32x4*)(xs16 + (size_t)b * 1024 + t * 8) = p;
    }
  } else if (blk < 4096) {
    cvt8(Wg, wgb, blk - 2048, t);
  } else if (blk < 4608) {
    cvt8(Wp, wpb, blk - 4096, t);
  } else {
    const int bid = blk - 4608;
    const int g = bid >> 6, rem = bid & 63;
    const int f0 = (rem & 15) * 64, r0 = (rem >> 4) * 64;
    const float* src = Wt + ((size_t)g * 256 + r0) * 1024 + f0;
#pragma unroll
    for (int i = 0; i < 16; ++i) {
      int idx = t + i * 256;
      int rl = idx >> 6, fl = idx & 63;
      tile[fl][rl] = f2bf(src[rl * 1024 + fl]);
    }
    __syncthreads();
    u16* dst = wtb + ((size_t)g * 1024 + f0) * 256 + r0;
#pragma unroll
    for (int i = 0; i < 4; ++i) {
      int idx = t + i * 256;
      int fl = idx >> 4, rq = idx & 15;
      u32x2 p;
      p[0] = (u32)tile[fl][rq * 4]     | ((u32)tile[fl][rq * 4 + 1] << 16);
      p[1] = (u32)tile[fl][rq * 4 + 2] | ((u32)tile[fl][rq * 4 + 3] << 16);
      *(u32x2*)(dst + fl * 256 + rq * 4) = p;
    }
  }
}

// ---- K2: ps16[b,q] = bf16( xs16·Wp16 + 64*bp ), 128x64 tiles, grid (16,16) --
__global__ __launch_bounds__(256) void k2_gemm(const u16* __restrict__ A,
                                               const u16* __restrict__ Bt,
                                               const float* __restrict__ bp,
                                               u16* __restrict__ C) {
  const int n0 = blockIdx.x * 64, m0 = blockIdx.y * 128;
  __shared__ u16 Al[128 * 32];
  __shared__ u16 Bl[64 * 32];
  const int t = threadIdx.x;
  const int w = t >> 6, l = t & 63;
  const int lr = l & 15, lh = l >> 4;
  f32x4 acc[2][4] = {};
  for (int kt = 0; kt < 1024; kt += 32) {
#pragma unroll
    for (int j = 0; j < 2; ++j) {
      int idx = t + j * 256;
      int row = idx >> 2, sl = idx & 3;
      GLD16(A + (size_t)(m0 + row) * 1024 + kt + sl * 8, Al + idx * 8);
    }
    {
      int row = t >> 2, sl = t & 3;
      GLD16(Bt + (size_t)(n0 + row) * 1024 + kt + sl * 8, Bl + t * 8);
    }
    __syncthreads();
    short8 af[2], bfr[4];
#pragma unroll
    for (int m = 0; m < 2; ++m)
      af[m] = *(const short8*)(Al + (w * 32 + m * 16 + lr) * 32 + lh * 8);
#pragma unroll
    for (int n = 0; n < 4; ++n)
      bfr[n] = *(const short8*)(Bl + (n * 16 + lr) * 32 + lh * 8);
#pragma unroll
    for (int m = 0; m < 2; ++m)
#pragma unroll
      for (int n = 0; n < 4; ++n)
        acc[m][n] = __builtin_amdgcn_mfma_f32_16x16x32_bf16(af[m], bfr[n],
                                                            acc[m][n], 0, 0, 0);
    __syncthreads();
  }
#pragma unroll
  for (int m = 0; m < 2; ++m)
#pragma unroll
    for (int n = 0; n < 4; ++n) {
      int col = n0 + n * 16 + lr;
      float bb = 64.0f * bp[col];
#pragma unroll
      for (int j = 0; j < 4; ++j)
        C[(size_t)(m0 + w * 32 + m * 16 + lh * 4 + j) * 1024 + col] =
            f2bf(acc[m][n][j] + bb);
    }
}

// -- K3: V16 = bf16( ps16·Wtt ), BK=64 slot-swizzled, grid 512 + XCD swizzle --
__global__ __launch_bounds__(256) void k3_gemm(const u16* __restrict__ A,
                                               const u16* __restrict__ Btt,
                                               u16* __restrict__ Vb) {
  const int id = blockIdx.x;
  const int wg = (id & 7) * 64 + (id >> 3);   // bijective XCD chunking (512=64x8)
  const int n0 = (wg & 7) * 128, m0 = ((wg >> 3) & 15) * 128, g = wg >> 7;
  const u16* Bg = Btt + (size_t)g * 1024 * 256;
  __shared__ u16 Al[128 * 64];
  __shared__ u16 Bl[128 * 64];
  const int t = threadIdx.x;
  const int w = t >> 6, l = t & 63;
  const int wr = w >> 1, wc = w & 1;
  const int lr = l & 15, lh = l >> 4;
  f32x4 acc[4][4] = {};
  for (int kt = 0; kt < 256; kt += 64) {
    // LDS[row][p] = G[row][p ^ (row&7)]  (linear dest, swizzled source slot)
#pragma unroll
    for (int j = 0; j < 4; ++j) {
      int idx = t + j * 256;
      int row = idx >> 3, sl = idx & 7;
      int ssl = sl ^ (row & 7);
      GLD16(A + (size_t)(m0 + row) * 1024 + g * 256 + kt + ssl * 8,
            Al + idx * 8);
      GLD16(Bg + (size_t)(n0 + row) * 256 + kt + ssl * 8, Bl + idx * 8);
    }
    __syncthreads();
    short8 af[4][2], bfr[4][2];
#pragma unroll
    for (int m = 0; m < 4; ++m) {
      int row = wr * 64 + m * 16 + lr;
#pragma unroll
      for (int ks = 0; ks < 2; ++ks)
        af[m][ks] =
            *(const short8*)(Al + row * 64 + (((ks * 4 + lh) ^ (row & 7)) * 8));
    }
#pragma unroll
    for (int n = 0; n < 4; ++n) {
      int row = wc * 64 + n * 16 + lr;
#pragma unroll
      for (int ks = 0; ks < 2; ++ks)
        bfr[n][ks] =
            *(const short8*)(Bl + row * 64 + (((ks * 4 + lh) ^ (row & 7)) * 8));
    }
#pragma unroll
    for (int m = 0; m < 4; ++m)
#pragma unroll
      for (int n = 0; n < 4; ++n) {
        acc[m][n] = __builtin_amdgcn_mfma_f32_16x16x32_bf16(
            af[m][0], bfr[n][0], acc[m][n], 0, 0, 0);
        acc[m][n] = __builtin_amdgcn_mfma_f32_16x16x32_bf16(
            af[m][1], bfr[n][1], acc[m][n], 0, 0, 0);
      }
    __syncthreads();
  }
  u16* Vg = Vb + (size_t)g * 2048 * 1024;
#pragma unroll
  for (int m = 0; m < 4; ++m)
#pragma unroll
    for (int n = 0; n < 4; ++n)
#pragma unroll
      for (int j = 0; j < 4; ++j)
        Vg[(size_t)(m0 + wr * 64 + m * 16 + lh * 4 + j) * 1024 +
           (n0 + wc * 64 + n * 16 + lr)] = f2bf(acc[m][n][j]);
}

// ---------------- K4 phase helpers ----------------
__device__ __forceinline__ void relation_phase(const char* xl, const u16* vb,
                                               float* relp, int w, int l) {
  const int lg = l >> 4, lr = l & 15;
  f32x4 racc[4] = {};
#pragma unroll
  for (int kp = 0; kp < 2; ++kp) {
    const int kt = kp * 512 + w * 32;
    short8 afr = {};
    if (lr < 4) afr = *(const short8*)(vb + lr * 1032 + kt + lg * 8);
#pragma unroll
    for (int nt = 0; nt < 4; ++nt) {
      int n = nt * 16 + lr;
      short8 bfrg = *(const short8*)(
          xl + n * 2048 + ((((kt >> 3) + lg) ^ (n & 7)) << 4));
      racc[nt] = __builtin_amdgcn_mfma_f32_16x16x32_bf16(afr, bfrg, racc[nt],
                                                         0, 0, 0);
    }
  }
  // D (16x16x32): col = lane&15, row = (lane>>4)*4 + reg; lanes<16 rows 0..3=g
  if (l < 16) {
#pragma unroll
    for (int nt = 0; nt < 4; ++nt)
#pragma unroll
      for (int j = 0; j < 4; ++j)
        relp[(w * 4 + j) * 64 + nt * 16 + lr] = racc[nt][j];
  }
}

__device__ __forceinline__ void softmax_phase(const float* relp, float* wsm,
                                              int t) {
  if (t < 256) {
    const int g = t >> 6, n = t & 63;
    float rel = 0.f;
#pragma unroll
    for (int ww = 0; ww < 16; ++ww) rel += relp[(ww * 4 + g) * 64 + n];
    rel *= SCALE_F;
    float mx = rel;
#pragma unroll
    for (int o = 32; o > 0; o >>= 1) mx = fmaxf(mx, __shfl_xor(mx, o, 64));
    float e = __expf(rel - mx);
    float s = e;
#pragma unroll
    for (int o = 32; o > 0; o >>= 1) s += __shfl_xor(s, o, 64);
    wsm[t] = e / s;
  }
}

__device__ __forceinline__ void agg_phase(const char* xl, const float* wsm,
                                          float* relp, u16* aggb, int b,
                                          int t) {
  const int hh = t >> 9, r = t & 511, g = r >> 7, f8 = r & 127;
  const float* wg = wsm + g * 64 + hh * 32;
  float a0 = 0, a1 = 0, a2 = 0, a3 = 0, a4 = 0, a5 = 0, a6 = 0, a7 = 0;
#pragma unroll 8
  for (int n0 = 0; n0 < 32; ++n0) {
    int n = hh * 32 + n0;
    float wv = wg[n0];
    u32x4 xp = *(const u32x4*)(xl + n * 2048 + ((f8 ^ (n & 7)) << 4));
    a0 = fmaf(bflo(xp[0]), wv, a0);
    a1 = fmaf(bfhi(xp[0]), wv, a1);
    a2 = fmaf(bflo(xp[1]), wv, a2);
    a3 = fmaf(bfhi(xp[1]), wv, a3);
    a4 = fmaf(bflo(xp[2]), wv, a4);
    a5 = fmaf(bfhi(xp[2]), wv, a5);
    a6 = fmaf(bflo(xp[3]), wv, a6);
    a7 = fmaf(bfhi(xp[3]), wv, a7);
  }
  if (hh) {
    f4 q0 = {a0, a1, a2, a3};
    f4 q1 = {a4, a5, a6, a7};
    *(f4*)(relp + r * 8) = q0;
    *(f4*)(relp + r * 8 + 4) = q1;
  }
  __syncthreads();
  if (!hh) {
    f4 q0 = *(const f4*)(relp + r * 8);
    f4 q1 = *(const f4*)(relp + r * 8 + 4);
    u32x4 p;
    p[0] = pk(a0 + q0[0], a1 + q0[1]);
    p[1] = pk(a2 + q0[2], a3 + q0[3]);
    p[2] = pk(a4 + q1[0], a5 + q1[1]);
    p[3] = pk(a6 + q1[2], a7 + q1[3]);
    *(u32x4*)(aggb + ((size_t)g * 2048 + b) * 1024 + f8 * 8) = p;
  }
}

// ------ K4: grid 256 (1 block/CU), 8 b's per block, steady-state pipeline ---
// LDS: xl 128K swizzled bf16 | vb 8256B | relp 16K | wsm 1K
#define K4_LDS (131072 + 8256 + 16384 + 1024)
__global__ __launch_bounds__(1024) void k4_fused(const char* __restrict__ xpre,
                                                 const u16* __restrict__ vb16,
                                                 u16* __restrict__ aggb) {
  extern __shared__ char sm[];
  char* xl = sm;
  u16* vb = (u16*)(sm + 131072);
  float* relp = (float*)(sm + 131072 + 8256);
  float* wsm = (float*)(sm + 131072 + 8256 + 16384);
  const int t = threadIdx.x;
  const int w = t >> 6, l = t & 63;
  // reverse chunk order: xpre tail was written last by K01 -> L3-hot first
  const int bbase = (255 - (int)blockIdx.x) * 8;

  // ---- cold stage: b0 x via DMA (swizzled per-lane SOURCE, linear dest) ----
  {
    int g = t >> 8, q = t & 255;
    u32x2 pv = *(const u32x2*)(vb16 + ((size_t)g * 2048 + bbase) * 1024 + q * 4);
    *(u32x2*)(vb + g * 1032 + q * 4) = pv;
  }
  const char* xg0 = xpre + (size_t)bbase * 131072;
#pragma unroll
  for (int i = 0; i < 8; ++i) {
    int o = (w * 8 + i) * 1024 + l * 16;
    GLD16(xg0 + SWZ(o), xl + o);
  }
  __syncthreads();

  u32x4 pf0, pf1, pf2, pf3, pf4, pf5, pf6, pf7;
  u32x2 pv1;
  for (int ib = 0; ib < 8; ++ib) {
    const int b = bbase + ib;
    // issue next-b prefetch; lands during this b's compute
    if (ib < 7) {
      const char* xg1 = xpre + (size_t)(b + 1) * 131072;
      pf0 = *(const u32x4*)(xg1 + SWZ(t * 16));
      pf1 = *(const u32x4*)(xg1 + SWZ(t * 16 + 16384));
      pf2 = *(const u32x4*)(xg1 + SWZ(t * 16 + 32768));
      pf3 = *(const u32x4*)(xg1 + SWZ(t * 16 + 49152));
      pf4 = *(const u32x4*)(xg1 + SWZ(t * 16 + 65536));
      pf5 = *(const u32x4*)(xg1 + SWZ(t * 16 + 81920));
      pf6 = *(const u32x4*)(xg1 + SWZ(t * 16 + 98304));
      pf7 = *(const u32x4*)(xg1 + SWZ(t * 16 + 114688));
      pv1 = *(const u32x2*)(vb16 + ((size_t)(t >> 8) * 2048 + (b + 1)) * 1024 +
                            (t & 255) * 4);
    }
    // ---- compute current b ----
    relation_phase(xl, vb, relp, w, l);
    __syncthreads();
    softmax_phase(relp, wsm, t);
    __syncthreads();
    agg_phase(xl, wsm, relp, aggb, b, t);
    __syncthreads();                     // all xl reads for this b done
    // ---- stage next b from regs ----
    if (ib < 7) {
      *(u32x4*)(xl + t * 16) = pf0;
      *(u32x4*)(xl + t * 16 + 16384) = pf1;
      *(u32x4*)(xl + t * 16 + 32768) = pf2;
      *(u32x4*)(xl + t * 16 + 49152) = pf3;
      *(u32x4*)(xl + t * 16 + 65536) = pf4;
      *(u32x4*)(xl + t * 16 + 81920) = pf5;
      *(u32x4*)(xl + t * 16 + 98304) = pf6;
      *(u32x4*)(xl + t * 16 + 114688) = pf7;
      *(u32x2*)(vb + (t >> 8) * 1032 + (t & 255) * 4) = pv1;
      __syncthreads();
    }
  }
}

// -- K5: h16 = bf16( agg·Wg^T ), BK=64 slot-swizzled, grid 512 + XCD swizzle --
__global__ __launch_bounds__(256) void k5_gemm(const u16* __restrict__ Ab,
                                               const u16* __restrict__ Bb,
                                               u16* __restrict__ H) {
  const int id = blockIdx.x;
  const int wg = (id & 7) * 64 + (id >> 3);   // per-XCD: g fixed, 4MB footprint
  const int n0 = (wg & 7) * 128, m0 = ((wg >> 3) & 15) * 128, g = wg >> 7;
  const u16* A = Ab + (size_t)g * 2048 * 1024;
  const u16* Bt = Bb + (size_t)g * 1024 * 1024;
  __shared__ u16 Al[128 * 64];
  __shared__ u16 Bl[128 * 64];
  const int t = threadIdx.x;
  const int w = t >> 6, l = t & 63;
  const int wr = w >> 1, wc = w & 1;
  const int lr = l & 15, lh = l >> 4;
  f32x4 acc[4][4] = {};
  for (int kt = 0; kt < 1024; kt += 64) {
    // LDS[row][p] = G[row][p ^ (row&7)]  (linear dest, swizzled source slot)
#pragma unroll
    for (int j = 0; j < 4; ++j) {
      int idx = t + j * 256;
      int row = idx >> 3, sl = idx & 7;
      int ssl = sl ^ (row & 7);
      GLD16(A + (size_t)(m0 + row) * 1024 + kt + ssl * 8, Al + idx * 8);
      GLD16(Bt + (size_t)(n0 + row) * 1024 + kt + ssl * 8, Bl + idx * 8);
    }
    __syncthreads();
    short8 af[4][2], bfr[4][2];
#pragma unroll
    for (int m = 0; m < 4; ++m) {
      int row = wr * 64 + m * 16 + lr;
#pragma unroll
      for (int ks = 0; ks < 2; ++ks)
        af[m][ks] =
            *(const short8*)(Al + row * 64 + (((ks * 4 + lh) ^ (row & 7)) * 8));
    }
#pragma unroll
    for (int n = 0; n < 4; ++n) {
      int row = wc * 64 + n * 16 + lr;
#pragma unroll
      for (int ks = 0; ks < 2; ++ks)
        bfr[n][ks] =
            *(const short8*)(Bl + row * 64 + (((ks * 4 + lh) ^ (row & 7)) * 8));
    }
#pragma unroll
    for (int m = 0; m < 4; ++m)
#pragma unroll
      for (int n = 0; n < 4; ++n) {
        acc[m][n] = __builtin_amdgcn_mfma_f32_16x16x32_bf16(
            af[m][0], bfr[n][0], acc[m][n], 0, 0, 0);
        acc[m][n] = __builtin_amdgcn_mfma_f32_16x16x32_bf16(
            af[m][1], bfr[n][1], acc[m][n], 0, 0, 0);
      }
    __syncthreads();
  }
  u16* Hg = H + (size_t)g * 2048 * 1024;
#pragma unroll
  for (int m = 0; m < 4; ++m)
#pragma unroll
    for (int n = 0; n < 4; ++n)
#pragma unroll
      for (int j = 0; j < 4; ++j)
        Hg[(size_t)(m0 + wr * 64 + m * 16 + lh * 4 + j) * 1024 +
           (n0 + wc * 64 + n * 16 + lr)] = f2bf(acc[m][n][j]);
}

// ---------------- K6: LayerNorm + ReLU + mean over g (bf16 H) ----------------
__global__ __launch_bounds__(256) void k6_ln(const u16* __restrict__ H,
                                             const float* __restrict__ gamma,
                                             const float* __restrict__ beta,
                                             float* __restrict__ out) {
  const int b = blockIdx.x, t = threadIdx.x;
  const int w = t >> 6, lane = t & 63;
  __shared__ float red[8];
  f4 acc = {0.f, 0.f, 0.f, 0.f};
  for (int g = 0; g < 4; ++g) {
    u32x2 hp = *(const u32x2*)(H + ((size_t)g * 2048 + b) * 1024 + t * 4);
    f4 hv = {bflo(hp[0]), bfhi(hp[0]), bflo(hp[1]), bfhi(hp[1])};
    float s = hv[0] + hv[1] + hv[2] + hv[3];
    float q = hv[0] * hv[0] + hv[1] * hv[1] + hv[2] * hv[2] + hv[3] * hv[3];
#pragma unroll
    for (int o = 32; o > 0; o >>= 1) {
      s += __shfl_xor(s, o, 64);
      q += __shfl_xor(q, o, 64);
    }
    if (lane == 0) { red[w] = s; red[4 + w] = q; }
    __syncthreads();
    s = red[0] + red[1] + red[2] + red[3];
    q = red[4] + red[5] + red[6] + red[7];
    float mean = s * (1.f / 1024.f);
    float var = q * (1.f / 1024.f) - mean * mean;
    float rstd = rsqrtf(var + 1e-5f);
    f4 gm = *(const f4*)(gamma + g * 1024 + t * 4);
    f4 bt = *(const f4*)(beta + g * 1024 + t * 4);
#pragma unroll
    for (int j = 0; j < 4; ++j) {
      float val = (hv[j] - mean) * rstd * gm[j] + bt[j];
      acc[j] += fmaxf(val, 0.f);
    }
    __syncthreads();
  }
  acc *= 0.25f;
  *(f4*)(out + (size_t)b * 1024 + t * 4) = acc;
}

extern "C" void kernel_launch(void* const* d_in, const int* in_sizes, int n_in,
                              void* d_out, int out_size, void* d_ws, size_t ws_size,
                              hipStream_t stream) {
  const float* x     = (const float*)d_in[0];
  const float* Wt    = (const float*)d_in[1];
  // d_in[2] = bt: n-constant in relation -> cancels in softmax, unused
  const float* Wp    = (const float*)d_in[3];
  const float* bp    = (const float*)d_in[4];
  const float* Wg    = (const float*)d_in[5];
  const float* gamma = (const float*)d_in[6];
  const float* beta  = (const float*)d_in[7];
  float* out = (float*)d_out;

  char* ws = (char*)d_ws;
  u16*   xs16 = (u16*)(ws);                          //  4 MiB
  u16*   ps16 = (u16*)(ws + (4u << 20));             //  4 MiB
  u16*   wpb  = (u16*)(ws + (8u << 20));             //  2 MiB
  u16*   wtb  = (u16*)(ws + (10u << 20));            //  2 MiB
  u16*   wgb  = (u16*)(ws + (12u << 20));            //  8 MiB
  u16*   vb16 = (u16*)(ws + (20u << 20));            // 16 MiB
  u16*   aggb = (u16*)(ws + (36u << 20));            // 16 MiB
  u16*   hb16 = (u16*)(ws + (52u << 20));            // 16 MiB
  char*  xpre = (char*)(ws + (68u << 20));           // 256 MiB (LINEAR bf16)

  hipFuncSetAttribute((const void*)k4_fused,
                      hipFuncAttributeMaxDynamicSharedMemorySize, K4_LDS);

  k01_prep<<<4864, 256, 0, stream>>>(x, Wg, Wp, Wt, xs16, xpre, wgb, wpb, wtb);
  k2_gemm<<<dim3(16, 16), 256, 0, stream>>>(xs16, wpb, bp, ps16);
  k3_gemm<<<512, 256, 0, stream>>>(ps16, wtb, vb16);
  k4_fused<<<256, 1024, K4_LDS, stream>>>(xpre, vb16, aggb);
  k5_gemm<<<512, 256, 0, stream>>>(aggb, wgb, hb16);
  k6_ln<<<2048, 256, 0, stream>>>(hb16, gamma, beta, out);
}